// Round 7
// baseline (291.411 us; speedup 1.0000x reference)
//
#include <hip/hip_runtime.h>
#include <hip/hip_cooperative_groups.h>

namespace cg = cooperative_groups;

// Problem constants: b=32, d=256, h=32, w=128
#define BB 32
#define DD 256
#define HW 4096
#define NSLICE (BB * DD)      // 8192 (b,d) slices of 4096 floats
#define EPS 1e-5f

#define CNBLK 512             // cooperative grid (512 was accepted in R6)
#define CSPB (NSLICE / CNBLK) // 16 slices per block, all sharing one b

typedef float floatx4 __attribute__((ext_vector_type(4)));

// ws layout (floats): [0,8192) slice sum | [8192,16384) slice sumsq | [16384,16416) per-b count
// Every slot is written before the sync point each call -> no zeroing needed.

// ---------------- Fused cooperative kernel: 1024 threads = 16 waves/block ----------------
__global__ void __launch_bounds__(1024, 8)
fused_kernel(const float* __restrict__ x, const int* __restrict__ mask,
             const float* __restrict__ gamma, const float* __restrict__ beta,
             float* __restrict__ ws, float* __restrict__ out) {
    const int blk = blockIdx.x;
    const int tid = threadIdx.x;          // 0..1023
    const int wave = tid >> 6, lane = tid & 63;
    const int slice0 = blk * CSPB;
    const int b = slice0 >> 8;            // 16 divides 256 -> all 16 slices share b
    const int d0 = slice0 & 255;

    __shared__ float ssum[CSPB][16], ssq[CSPB][16], scnt[16];
    __shared__ float s_scale[CSPB], s_bias[CSPB];

    // This b's mask: one int4 per thread (4096 ints = 1024 int4), kept in regs
    // and reused by phase 1 and phase 3.
    const int4 mv = reinterpret_cast<const int4*>(mask + b * HW)[tid];

    // Per-b unmasked count
    {
        float cnt = (mv.x ? 0.f : 1.f) + (mv.y ? 0.f : 1.f)
                  + (mv.z ? 0.f : 1.f) + (mv.w ? 0.f : 1.f);
#pragma unroll
        for (int off = 32; off > 0; off >>= 1) cnt += __shfl_down(cnt, off);
        if (lane == 0) scnt[wave] = cnt;
    }

    // ---- Phase 1: per-slice partial sums (one float4 per thread per slice) ----
    const float4* xb = reinterpret_cast<const float4*>(x + (size_t)slice0 * HW);
#pragma unroll
    for (int s = 0; s < CSPB; ++s) {
        float4 xv = xb[s * 1024 + tid];
        float sum = 0.f, sq = 0.f;
        if (!mv.x) { sum += xv.x; sq += xv.x * xv.x; }
        if (!mv.y) { sum += xv.y; sq += xv.y * xv.y; }
        if (!mv.z) { sum += xv.z; sq += xv.z * xv.z; }
        if (!mv.w) { sum += xv.w; sq += xv.w * xv.w; }
#pragma unroll
        for (int off = 32; off > 0; off >>= 1) {
            sum += __shfl_down(sum, off);
            sq  += __shfl_down(sq, off);
        }
        if (lane == 0) { ssum[s][wave] = sum; ssq[s][wave] = sq; }
    }
    __syncthreads();
    // Reduce 16 wave-partials per slice: threads 0..255, group of 16 per slice.
    if (tid < 256) {
        const int s = tid >> 4, w = tid & 15;
        float ts = ssum[s][w], tq = ssq[s][w];
#pragma unroll
        for (int off = 8; off > 0; off >>= 1) {
            ts += __shfl_down(ts, off, 16);
            tq += __shfl_down(tq, off, 16);
        }
        if (w == 0) {
            ws[slice0 + s] = ts;
            ws[NSLICE + slice0 + s] = tq;
        }
    }
    if (tid == 0 && d0 == 0) {
        float tc = 0.f;
#pragma unroll
        for (int i = 0; i < 16; ++i) tc += scnt[i];
        ws[2 * NSLICE + b] = tc;
    }
    __threadfence();
    cg::this_grid().sync();

    // ---- Phase 2: finalize ONLY this block's 16 channels ----
    // wave g owns channel d0+g; lanes 0..31 gather the 32 per-b partials.
    {
        const int ch = d0 + wave;
        const int l = lane;
        float ps = (l < 32) ? ws[l * DD + ch] : 0.f;
        float pq = (l < 32) ? ws[NSLICE + l * DD + ch] : 0.f;
        float pc = (l < 32) ? ws[2 * NSLICE + l] : 0.f;
#pragma unroll
        for (int off = 32; off > 0; off >>= 1) {
            ps += __shfl_down(ps, off);
            pq += __shfl_down(pq, off);
            pc += __shfl_down(pc, off);
        }
        if (l == 0) {
            pc = fmaxf(pc, 1.0f);
            const float mean = ps / pc;
            const float var = fmaxf(pq / pc - mean * mean, 0.0f);
            const float sc = rsqrtf(var + EPS) * gamma[ch];
            s_scale[wave] = sc;
            s_bias[wave] = beta[ch] - mean * sc;
        }
    }
    __syncthreads();

    // ---- Phase 3: normalize own slices (x re-read hits L3; nt-store out) ----
    floatx4* ob = reinterpret_cast<floatx4*>(out + (size_t)slice0 * HW);
#pragma unroll
    for (int s = 0; s < CSPB; ++s) {
        const float sc = s_scale[s], bi = s_bias[s];
        float4 xv = xb[s * 1024 + tid];
        floatx4 o;
        o.x = mv.x ? xv.x : xv.x * sc + bi;
        o.y = mv.y ? xv.y : xv.y * sc + bi;
        o.z = mv.z ? xv.z : xv.z * sc + bi;
        o.w = mv.w ? xv.w : xv.w * sc + bi;
        __builtin_nontemporal_store(o, &ob[s * 1024 + tid]);
    }
}

// ---------------- Fallback: proven two-kernel path (R4, 70.0 us) ----------------
__global__ void __launch_bounds__(256)
stats_kernel(const float* __restrict__ x, const int* __restrict__ mask,
             float* __restrict__ ws) {
    const int slice = blockIdx.x;
    const int b = slice >> 8;
    const int d = slice & 255;
    const float4* xs = reinterpret_cast<const float4*>(
        x + (size_t)b * (DD * HW) + (size_t)d * HW);
    const int4* ms = reinterpret_cast<const int4*>(mask + b * HW);
    const int tid = threadIdx.x;

    float sum = 0.f, sq = 0.f, cnt = 0.f;
#pragma unroll
    for (int j = 0; j < 4; ++j) {
        const int v = j * 256 + tid;
        float4 xv = xs[v];
        int4 mv = ms[v];
        if (!mv.x) { sum += xv.x; sq += xv.x * xv.x; cnt += 1.f; }
        if (!mv.y) { sum += xv.y; sq += xv.y * xv.y; cnt += 1.f; }
        if (!mv.z) { sum += xv.z; sq += xv.z * xv.z; cnt += 1.f; }
        if (!mv.w) { sum += xv.w; sq += xv.w * xv.w; cnt += 1.f; }
    }
#pragma unroll
    for (int off = 32; off > 0; off >>= 1) {
        sum += __shfl_down(sum, off);
        sq  += __shfl_down(sq, off);
        cnt += __shfl_down(cnt, off);
    }
    __shared__ float fsum[4], fsq[4], fcnt[4];
    const int wave = tid >> 6, lane = tid & 63;
    if (lane == 0) { fsum[wave] = sum; fsq[wave] = sq; fcnt[wave] = cnt; }
    __syncthreads();
    if (tid == 0) {
        float ts = 0.f, tq = 0.f, tc = 0.f;
#pragma unroll
        for (int i = 0; i < 4; ++i) { ts += fsum[i]; tq += fsq[i]; tc += fcnt[i]; }
        ws[slice] = ts;
        ws[NSLICE + slice] = tq;
        if (d == 0) ws[2 * NSLICE + b] = tc;
    }
}

__global__ void __launch_bounds__(256)
apply_kernel(const float* __restrict__ x, const int* __restrict__ mask,
             const float* __restrict__ ws, const float* __restrict__ gamma,
             const float* __restrict__ beta, float* __restrict__ out) {
    __shared__ float s_scale[DD], s_bias[DD];
    const int tid = threadIdx.x;

    float cnt = 0.f;
#pragma unroll
    for (int b = 0; b < BB; ++b) cnt += ws[2 * NSLICE + b];
    cnt = fmaxf(cnt, 1.0f);
    float sum = 0.f, sq = 0.f;
#pragma unroll
    for (int b = 0; b < BB; ++b) {
        sum += ws[b * DD + tid];
        sq  += ws[NSLICE + b * DD + tid];
    }
    const float mean = sum / cnt;
    const float var = fmaxf(sq / cnt - mean * mean, 0.0f);
    const float sc = rsqrtf(var + EPS) * gamma[tid];
    s_scale[tid] = sc;
    s_bias[tid] = beta[tid] - mean * sc;
    __syncthreads();

    const int nvec = (BB * DD * HW) / 4;
    const int stride = gridDim.x * blockDim.x;
    floatx4* __restrict__ ov = reinterpret_cast<floatx4*>(out);
    for (int v = blockIdx.x * blockDim.x + tid; v < nvec; v += stride) {
        const int e = v << 2;
        const int bidx = e >> 20;
        const int rem = e & (DD * HW - 1);
        const int d = rem >> 12;
        const int pos = rem & 4095;
        float4 xv = reinterpret_cast<const float4*>(x)[v];
        int4 mv = reinterpret_cast<const int4*>(mask)[(bidx * HW + pos) >> 2];
        const float s = s_scale[d], bi = s_bias[d];
        floatx4 o;
        o.x = mv.x ? xv.x : xv.x * s + bi;
        o.y = mv.y ? xv.y : xv.y * s + bi;
        o.z = mv.z ? xv.z : xv.z * s + bi;
        o.w = mv.w ? xv.w : xv.w * s + bi;
        __builtin_nontemporal_store(o, &ov[v]);
    }
}

extern "C" void kernel_launch(void* const* d_in, const int* in_sizes, int n_in,
                              void* d_out, int out_size, void* d_ws, size_t ws_size,
                              hipStream_t stream) {
    const float* x     = (const float*)d_in[0];
    const int*   mask  = (const int*)d_in[1];
    const float* gamma = (const float*)d_in[2];
    const float* beta  = (const float*)d_in[3];
    float* out = (float*)d_out;
    float* ws  = (float*)d_ws;

    void* args[] = {(void*)&x, (void*)&mask, (void*)&gamma, (void*)&beta,
                    (void*)&ws, (void*)&out};
    hipError_t err = hipLaunchCooperativeKernel((const void*)fused_kernel,
                                                dim3(CNBLK), dim3(1024),
                                                args, 0, stream);
    if (err != hipSuccess) {
        // Deterministic fallback: proven two-kernel path.
        stats_kernel<<<NSLICE, 256, 0, stream>>>(x, mask, ws);
        apply_kernel<<<2048, 256, 0, stream>>>(x, mask, ws, gamma, beta, out);
    }
}

// Round 8
// 69.211 us; speedup vs baseline: 4.2105x; 4.2105x over previous
//
#include <hip/hip_runtime.h>

// Problem constants: b=32, d=256, h=32, w=128
#define BB 32
#define DD 256
#define HW 4096
#define DHW (DD * HW)        // 2^20
#define NSLICE (BB * DD)     // 8192
#define TOTAL (BB * DHW)     // 33554432
#define EPS 1e-5f

// ws layout (floats)
#define WS_SUM   0
#define WS_SQ    NSLICE
#define WS_CNT   (2 * NSLICE)          // 32 per-b counts
#define WS_SCALE (2 * NSLICE + 64)
#define WS_BIAS  (2 * NSLICE + 64 + DD)
// Every slot consumed is written earlier in the same call -> no zeroing needed.

typedef float floatx4 __attribute__((ext_vector_type(4)));

__global__ void __launch_bounds__(256)
stats_kernel(const float* __restrict__ x, const int* __restrict__ mask,
             float* __restrict__ ws) {
    const int slice = blockIdx.x;          // 8192 (b,d) slices
    const int b = slice >> 8;
    const int d = slice & 255;
    const float4* xs = reinterpret_cast<const float4*>(
        x + (size_t)b * DHW + (size_t)d * HW);
    const int4* ms = reinterpret_cast<const int4*>(mask + b * HW);
    const int tid = threadIdx.x;

    float sum = 0.f, sq = 0.f, cnt = 0.f;
#pragma unroll
    for (int j = 0; j < 4; ++j) {
        const int v = j * 256 + tid;
        float4 xv = xs[v];
        int4 mv = ms[v];
        if (!mv.x) { sum += xv.x; sq += xv.x * xv.x; cnt += 1.f; }
        if (!mv.y) { sum += xv.y; sq += xv.y * xv.y; cnt += 1.f; }
        if (!mv.z) { sum += xv.z; sq += xv.z * xv.z; cnt += 1.f; }
        if (!mv.w) { sum += xv.w; sq += xv.w * xv.w; cnt += 1.f; }
    }
#pragma unroll
    for (int off = 32; off > 0; off >>= 1) {
        sum += __shfl_down(sum, off);
        sq  += __shfl_down(sq, off);
        cnt += __shfl_down(cnt, off);
    }
    __shared__ float fsum[4], fsq[4], fcnt[4];
    const int wave = tid >> 6, lane = tid & 63;
    if (lane == 0) { fsum[wave] = sum; fsq[wave] = sq; fcnt[wave] = cnt; }
    __syncthreads();
    if (tid == 0) {
        float ts = 0.f, tq = 0.f, tc = 0.f;
#pragma unroll
        for (int i = 0; i < 4; ++i) { ts += fsum[i]; tq += fsq[i]; tc += fcnt[i]; }
        ws[WS_SUM + slice] = ts;           // disjoint slots: no atomics, no memset
        ws[WS_SQ + slice] = tq;
        if (d == 0) ws[WS_CNT + b] = tc;
    }
}

// One tiny block: reduce 32 per-b partials per channel -> scale/bias[256].
__global__ void __launch_bounds__(256)
finalize_kernel(const float* __restrict__ gamma, const float* __restrict__ beta,
                float* __restrict__ ws) {
    const int d = threadIdx.x;
    float cnt = 0.f;
#pragma unroll
    for (int b = 0; b < BB; ++b) cnt += ws[WS_CNT + b];
    cnt = fmaxf(cnt, 1.0f);
    float sum = 0.f, sq = 0.f;
#pragma unroll
    for (int b = 0; b < BB; ++b) {
        sum += ws[WS_SUM + b * DD + d];
        sq  += ws[WS_SQ + b * DD + d];
    }
    const float mean = sum / cnt;
    const float var = fmaxf(sq / cnt - mean * mean, 0.0f);
    const float sc = rsqrtf(var + EPS) * gamma[d];
    ws[WS_SCALE + d] = sc;
    ws[WS_BIAS + d] = beta[d] - mean * sc;
}

__global__ void __launch_bounds__(256)
apply_kernel(const float* __restrict__ x, const int* __restrict__ mask,
             const float* __restrict__ ws, float* __restrict__ out) {
    __shared__ float s_scale[DD], s_bias[DD];
    const int tid = threadIdx.x;
    s_scale[tid] = ws[WS_SCALE + tid];     // 1 KB coalesced prologue
    s_bias[tid] = ws[WS_BIAS + tid];
    __syncthreads();

    // Reversed chunk order: block i handles chunk (last-i). The tail of x was
    // read most recently by stats_kernel -> consume it first, staying ahead of
    // the LRU eviction front created by our own output writes.
    const int chunk = (gridDim.x - 1) - blockIdx.x;
    const int cb = chunk * 4096;           // float4 base; 4096 float4s per chunk
    floatx4* __restrict__ ov = reinterpret_cast<floatx4*>(out);
#pragma unroll
    for (int j = 0; j < 16; ++j) {
        const int v = cb + j * 256 + tid;
        const int e = v << 2;              // element index
        const int bidx = e >> 20;
        const int rem = e & (DHW - 1);
        const int d = rem >> 12;           // wave-uniform -> LDS broadcast
        const int pos = rem & 4095;
        float4 xv = reinterpret_cast<const float4*>(x)[v];
        int4 mv = reinterpret_cast<const int4*>(mask)[(bidx * HW + pos) >> 2];
        const float s = s_scale[d], bi = s_bias[d];
        floatx4 o;
        o.x = mv.x ? xv.x : xv.x * s + bi;
        o.y = mv.y ? xv.y : xv.y * s + bi;
        o.z = mv.z ? xv.z : xv.z * s + bi;
        o.w = mv.w ? xv.w : xv.w * s + bi;
        __builtin_nontemporal_store(o, &ov[v]);
    }
}

extern "C" void kernel_launch(void* const* d_in, const int* in_sizes, int n_in,
                              void* d_out, int out_size, void* d_ws, size_t ws_size,
                              hipStream_t stream) {
    const float* x     = (const float*)d_in[0];
    const int*   mask  = (const int*)d_in[1];
    const float* gamma = (const float*)d_in[2];
    const float* beta  = (const float*)d_in[3];
    float* out = (float*)d_out;
    float* ws  = (float*)d_ws;

    stats_kernel<<<NSLICE, 256, 0, stream>>>(x, mask, ws);
    finalize_kernel<<<1, 256, 0, stream>>>(gamma, beta, ws);
    apply_kernel<<<2048, 256, 0, stream>>>(x, mask, ws, out);
}